// Round 5
// baseline (12223.169 us; speedup 1.0000x reference)
//
#include <hip/hip_runtime.h>
#include <utility>

#define H 20

// Raw v_rcp_f32 (~1 ulp); threshold is 1.9e-3, impact ~1e-7.
__device__ __forceinline__ float fast_rcp(float x) { return __builtin_amdgcn_rcpf(x); }
__device__ __forceinline__ float fsigmoid(float x) { return fast_rcp(1.0f + __expf(-x)); }
__device__ __forceinline__ float ftanh(float x) {
    float e = __expf(2.0f * x);
    return 1.0f - 2.0f * fast_rcp(e + 1.0f);
}

// ---- LDS weight arena (floats). All big arrays 16B-aligned so per-gate
// consecutive weights merge into ds_read_b128 (broadcast: all lanes same
// address -> conflict-free, 16B unique/instr).
constexpr int OFF_Wih1_0 = 0;                         // 4H x 16 = 1280
constexpr int OFF_Whh1_0 = OFF_Wih1_0 + 4 * H * 16;   // 1280: 4H x H = 1600
constexpr int OFF_b1_0   = OFF_Whh1_0 + 4 * H * H;    // 2880: 80
constexpr int OFF_Wih1_1 = OFF_b1_0   + 4 * H;        // 2960: 1600
constexpr int OFF_Whh1_1 = OFF_Wih1_1 + 4 * H * H;    // 4560: 1600
constexpr int OFF_b1_1   = OFF_Whh1_1 + 4 * H * H;    // 6160: 80
constexpr int OFF_Wih2_0 = OFF_b1_1   + 4 * H;        // 6240: 4H x 4 = 320
constexpr int OFF_Whh2_0 = OFF_Wih2_0 + 4 * H * 4;    // 6560: 1600
constexpr int OFF_b2_0   = OFF_Whh2_0 + 4 * H * H;    // 8160: 80
constexpr int OFF_Wih2_1 = OFF_b2_0   + 4 * H;        // 8240: 1600
constexpr int OFF_Whh2_1 = OFF_Wih2_1 + 4 * H * H;    // 9840: 1600
constexpr int OFF_b2_1   = OFF_Whh2_1 + 4 * H * H;    // 11440: 80
constexpr int OFF_fW1    = OFF_b2_1   + 4 * H;        // 11520: 10 x 20 = 200
constexpr int OFF_fb1    = OFF_fW1 + 10 * H;          // 11720: 10
constexpr int OFF_fW2    = OFF_fb1 + 10;              // 11730: 100
constexpr int OFF_fb2    = OFF_fW2 + 100;             // 11830: 10
constexpr int OFF_fW3    = OFF_fb2 + 10;              // 11840: 10
constexpr int OFF_fb3    = OFF_fW3 + 10;              // 11850: 1
constexpr int LDS_FLOATS = OFF_fb3 + 1;               // 11851 (~47.4 KB)

// ---- fold-expression cells: every index compile-time (SROA-proof, R4
// verified: WRITE_SIZE fell to the 2MB output => no scratch). Weight source
// is LDS -> ds_read with immediate offsets, fine-grained lgkmcnt pipelining.
template <int IN, size_t U, size_t... K>
__device__ __forceinline__ void dot4(const float* W, const float (&v)[IN],
                                     float& gi, float& gf, float& gg, float& go,
                                     std::index_sequence<K...>) {
    ((gi = fmaf(W[(0 * H + U) * IN + K], v[K], gi)), ...);
    ((gf = fmaf(W[(1 * H + U) * IN + K], v[K], gf)), ...);
    ((gg = fmaf(W[(2 * H + U) * IN + K], v[K], gg)), ...);
    ((go = fmaf(W[(3 * H + U) * IN + K], v[K], go)), ...);
}

template <int IN, size_t U>
__device__ __forceinline__ void cell_unit(const float* Wih, const float* Whh,
                                          const float* bias,
                                          const float (&x)[IN], const float (&h)[H],
                                          float (&c)[H], float (&hn)[H]) {
    float gi = bias[0 * H + U];
    float gf = bias[1 * H + U];
    float gg = bias[2 * H + U];
    float go = bias[3 * H + U];
    dot4<IN, U>(Wih, x, gi, gf, gg, go, std::make_index_sequence<IN>{});
    dot4<H, U>(Whh, h, gi, gf, gg, go, std::make_index_sequence<H>{});
    float cn = fsigmoid(gf) * c[U] + fsigmoid(gi) * ftanh(gg);
    c[U] = cn;
    hn[U] = fsigmoid(go) * ftanh(cn);
}

template <int IN, size_t... U>
__device__ __forceinline__ void cell_impl(const float* Wih, const float* Whh,
                                          const float* bias,
                                          const float (&x)[IN], float (&h)[H], float (&c)[H],
                                          std::index_sequence<U...>) {
    float hn[H];
    (cell_unit<IN, U>(Wih, Whh, bias, x, h, c, hn), ...);
    ((h[U] = hn[U]), ...);
}

template <int IN>
__device__ __forceinline__ void cell(const float* Wih, const float* Whh,
                                     const float* bias,
                                     const float (&x)[IN], float (&h)[H], float (&c)[H]) {
    cell_impl<IN>(Wih, Whh, bias, x, h, c, std::make_index_sequence<H>{});
}

template <size_t J, int LD, int NV, size_t... K>
__device__ __forceinline__ float mlp_dot(const float* W, const float (&v)[NV],
                                         float a, std::index_sequence<K...>) {
    ((a = fmaf(W[J * LD + K], v[K], a)), ...);
    return a;
}

template <size_t... J>
__device__ __forceinline__ void mlp_l1(const float* W, const float* b,
                                       const float (&h)[H], float (&z)[10], std::index_sequence<J...>) {
    ((z[J] = fmaxf(mlp_dot<J, H>(W, h, b[J], std::make_index_sequence<H>{}), 0.f)), ...);
}
template <size_t... J>
__device__ __forceinline__ void mlp_l2(const float* W, const float* b,
                                       const float (&z1)[10], float (&z2)[10], std::index_sequence<J...>) {
    ((z2[J] = fmaxf(mlp_dot<J, 10>(W, z1, b[J], std::make_index_sequence<10>{}), 0.f)), ...);
}

// No occupancy directive games: grid = 512 blocks = 2 blocks/CU caps us at
// 2 waves/SIMD regardless, so VGPR up to 256 is free headroom for the
// compiler to buffer/hoist ds_reads.
__global__ void __launch_bounds__(256) lstm_ar_kernel(
    const float* __restrict__ y_past, const float* __restrict__ x_past,
    const float* __restrict__ u_past, const float* __restrict__ s_past,
    const float* __restrict__ u_future,
    const float* __restrict__ Wih1_0, const float* __restrict__ Whh1_0, const float* __restrict__ b1_0,
    const float* __restrict__ Wih1_1, const float* __restrict__ Whh1_1, const float* __restrict__ b1_1,
    const float* __restrict__ Wih2_0, const float* __restrict__ Whh2_0, const float* __restrict__ b2_0,
    const float* __restrict__ Wih2_1, const float* __restrict__ Whh2_1, const float* __restrict__ b2_1,
    const float* __restrict__ fW1, const float* __restrict__ fb1,
    const float* __restrict__ fW2, const float* __restrict__ fb2,
    const float* __restrict__ fW3, const float* __restrict__ fb3,
    float* __restrict__ out, int B) {
    __shared__ __align__(16) float smem[LDS_FLOATS];
    const int tid = threadIdx.x;

    // ---- stage all weights into LDS (one-time; 47.4 KB/block, blocks read
    // the same 47 KB -> L2-served after first touch) ----
    auto stage = [&](const float* src, int off, int n) {
        for (int i = tid; i < n; i += 256) smem[off + i] = src[i];
    };
    stage(Wih1_0, OFF_Wih1_0, 4 * H * 16);
    stage(Whh1_0, OFF_Whh1_0, 4 * H * H);
    stage(b1_0,   OFF_b1_0,   4 * H);
    stage(Wih1_1, OFF_Wih1_1, 4 * H * H);
    stage(Whh1_1, OFF_Whh1_1, 4 * H * H);
    stage(b1_1,   OFF_b1_1,   4 * H);
    stage(Wih2_0, OFF_Wih2_0, 4 * H * 4);
    stage(Whh2_0, OFF_Whh2_0, 4 * H * H);
    stage(b2_0,   OFF_b2_0,   4 * H);
    stage(Wih2_1, OFF_Wih2_1, 4 * H * H);
    stage(Whh2_1, OFF_Whh2_1, 4 * H * H);
    stage(b2_1,   OFF_b2_1,   4 * H);
    stage(fW1,    OFF_fW1,    10 * H);
    stage(fb1,    OFF_fb1,    10);
    stage(fW2,    OFF_fW2,    100);
    stage(fb2,    OFF_fb2,    10);
    stage(fW3,    OFF_fW3,    10);
    stage(fb3,    OFF_fb3,    1);
    __syncthreads();

    int b = blockIdx.x * blockDim.x + tid;
    if (b >= B) return;   // B % 256 == 0, so no thread skips the barrier above

    float h0[H], c0[H], h1[H], c1[H];
    {
        auto zero = [&](auto... u) { ((h0[u] = 0.f, c0[u] = 0.f, h1[u] = 0.f, c1[u] = 0.f), ...); };
        zero(0,1,2,3,4,5,6,7,8,9,10,11,12,13,14,15,16,17,18,19);
    }

    // ---- encoder over lookback T=8 (input = concat[y,x,u,s] = 16 feats) ----
    for (int t = 0; t < 8; ++t) {
        float x[16];
        x[0] = y_past[b * 8 + t];
        {   // x_past row: 8 contiguous floats -> two float4 loads
            const float4* p = (const float4*)(x_past + (size_t)(b * 8 + t) * 8);
            float4 a0 = p[0], a1 = p[1];
            x[1] = a0.x; x[2] = a0.y; x[3] = a0.z; x[4] = a0.w;
            x[5] = a1.x; x[6] = a1.y; x[7] = a1.z; x[8] = a1.w;
        }
        {   // u_past row: 4 contiguous floats
            const float4* p = (const float4*)(u_past + (size_t)(b * 8 + t) * 4);
            float4 a0 = p[0];
            x[9] = a0.x; x[10] = a0.y; x[11] = a0.z; x[12] = a0.w;
        }
        {   // s_past row: 3 floats
            const float* p = s_past + (size_t)(b * 8 + t) * 3;
            x[13] = p[0]; x[14] = p[1]; x[15] = p[2];
        }
        cell<16>(smem + OFF_Wih1_0, smem + OFF_Whh1_0, smem + OFF_b1_0, x, h0, c0);
        cell<H>(smem + OFF_Wih1_1, smem + OFF_Whh1_1, smem + OFF_b1_1, h0, h1, c1);
    }

    // ---- decoder over lookahead T=4 (input = u_future, 4 feats) + MLP head ----
    for (int t = 0; t < 4; ++t) {
        float x[4];
        {
            const float4* p = (const float4*)(u_future + (size_t)(b * 4 + t) * 4);
            float4 a0 = p[0];
            x[0] = a0.x; x[1] = a0.y; x[2] = a0.z; x[3] = a0.w;
        }
        cell<4>(smem + OFF_Wih2_0, smem + OFF_Whh2_0, smem + OFF_b2_0, x, h0, c0);
        cell<H>(smem + OFF_Wih2_1, smem + OFF_Whh2_1, smem + OFF_b2_1, h0, h1, c1);

        // FCNN 20 -> 10 -> 10 -> 1
        float z1[10], z2[10];
        mlp_l1(smem + OFF_fW1, smem + OFF_fb1, h1, z1, std::make_index_sequence<10>{});
        mlp_l2(smem + OFF_fW2, smem + OFF_fb2, z1, z2, std::make_index_sequence<10>{});
        float o = mlp_dot<0, 10>(smem + OFF_fW3, z2, smem[OFF_fb3], std::make_index_sequence<10>{});
        out[b * 4 + t] = o;
    }
}

extern "C" void kernel_launch(void* const* d_in, const int* in_sizes, int n_in,
                              void* d_out, int out_size, void* d_ws, size_t ws_size,
                              hipStream_t stream) {
    (void)n_in; (void)d_ws; (void)ws_size;
    const float* y_past   = (const float*)d_in[0];
    const float* x_past   = (const float*)d_in[1];
    const float* u_past   = (const float*)d_in[2];
    const float* s_past   = (const float*)d_in[3];
    const float* u_future = (const float*)d_in[4];
    const float* Wih1_0 = (const float*)d_in[5];
    const float* Whh1_0 = (const float*)d_in[6];
    const float* b1_0   = (const float*)d_in[7];
    const float* Wih1_1 = (const float*)d_in[8];
    const float* Whh1_1 = (const float*)d_in[9];
    const float* b1_1   = (const float*)d_in[10];
    const float* Wih2_0 = (const float*)d_in[11];
    const float* Whh2_0 = (const float*)d_in[12];
    const float* b2_0   = (const float*)d_in[13];
    const float* Wih2_1 = (const float*)d_in[14];
    const float* Whh2_1 = (const float*)d_in[15];
    const float* b2_1   = (const float*)d_in[16];
    const float* fW1 = (const float*)d_in[17];
    const float* fb1 = (const float*)d_in[18];
    const float* fW2 = (const float*)d_in[19];
    const float* fb2 = (const float*)d_in[20];
    const float* fW3 = (const float*)d_in[21];
    const float* fb3 = (const float*)d_in[22];
    float* out = (float*)d_out;

    int B = in_sizes[0] / 8;  // y_past is [B,8,1]
    (void)out_size;

    dim3 block(256);
    dim3 grid((B + 255) / 256);
    lstm_ar_kernel<<<grid, block, 0, stream>>>(
        y_past, x_past, u_past, s_past, u_future,
        Wih1_0, Whh1_0, b1_0, Wih1_1, Whh1_1, b1_1,
        Wih2_0, Whh2_0, b2_0, Wih2_1, Whh2_1, b2_1,
        fW1, fb1, fW2, fb2, fW3, fb3, out, B);
}

// Round 6
// 1308.422 us; speedup vs baseline: 9.3419x; 9.3419x over previous
//
#include <hip/hip_runtime.h>
#include <utility>

#define H 20

// Raw v_rcp_f32 (~1 ulp); threshold is 1.9e-3, impact ~1e-7.
__device__ __forceinline__ float fast_rcp(float x) { return __builtin_amdgcn_rcpf(x); }
__device__ __forceinline__ float fsigmoid(float x) { return fast_rcp(1.0f + __expf(-x)); }
__device__ __forceinline__ float ftanh(float x) {
    float e = __expf(2.0f * x);
    return 1.0f - 2.0f * fast_rcp(e + 1.0f);
}

// ---- LDS weight arena (floats). Rows are 16B-aligned (IN*4B multiple of 16)
// so per-gate-row reads merge into ds_read_b128. Arena < 64KB => all offsets
// fit the 16-bit ds immediate.
constexpr int OFF_Wih1_0 = 0;                         // 4H x 16 = 1280
constexpr int OFF_Whh1_0 = OFF_Wih1_0 + 4 * H * 16;   // 1280: 1600
constexpr int OFF_b1_0   = OFF_Whh1_0 + 4 * H * H;    // 2880: 80
constexpr int OFF_Wih1_1 = OFF_b1_0   + 4 * H;        // 2960: 1600
constexpr int OFF_Whh1_1 = OFF_Wih1_1 + 4 * H * H;    // 4560: 1600
constexpr int OFF_b1_1   = OFF_Whh1_1 + 4 * H * H;    // 6160: 80
constexpr int OFF_Wih2_0 = OFF_b1_1   + 4 * H;        // 6240: 320
constexpr int OFF_Whh2_0 = OFF_Wih2_0 + 4 * H * 4;    // 6560: 1600
constexpr int OFF_b2_0   = OFF_Whh2_0 + 4 * H * H;    // 8160: 80
constexpr int OFF_Wih2_1 = OFF_b2_0   + 4 * H;        // 8240: 1600
constexpr int OFF_Whh2_1 = OFF_Wih2_1 + 4 * H * H;    // 9840: 1600
constexpr int OFF_b2_1   = OFF_Whh2_1 + 4 * H * H;    // 11440: 80
constexpr int OFF_fW1    = OFF_b2_1   + 4 * H;        // 11520: 200
constexpr int OFF_fb1    = OFF_fW1 + 10 * H;          // 11720: 10
constexpr int OFF_fW2    = OFF_fb1 + 10;              // 11730: 100
constexpr int OFF_fb2    = OFF_fW2 + 100;             // 11830: 10
constexpr int OFF_fW3    = OFF_fb2 + 10;              // 11840: 10
constexpr int OFF_fb3    = OFF_fW3 + 10;              // 11850: 1
constexpr int LDS_FLOATS = OFF_fb3 + 1;               // 11851 (~47.4 KB)

// R5 lesson: LDS weight loads are loop-invariant -> LICM hoisted thousands of
// ds_read results -> 256 VGPR + 12.4GB scratch re-reads from HBM. Fix: every
// LDS index includes a runtime base 'wb' that an empty asm re-opaques each
// timestep, so no ds_read can be hoisted across iterations. smem is indexed
// ONLY as the __shared__ array (addrspace(3) preserved; R5's generic-pointer
// flat path avoided).

template <int WOFF, int IN, size_t U, size_t... K>
__device__ __forceinline__ void dot4(const float (&sm)[LDS_FLOATS], int wb, const float (&v)[IN],
                                     float& gi, float& gf, float& gg, float& go,
                                     std::index_sequence<K...>) {
    ((gi = fmaf(sm[wb + WOFF + (0 * H + U) * IN + K], v[K], gi)), ...);
    ((gf = fmaf(sm[wb + WOFF + (1 * H + U) * IN + K], v[K], gf)), ...);
    ((gg = fmaf(sm[wb + WOFF + (2 * H + U) * IN + K], v[K], gg)), ...);
    ((go = fmaf(sm[wb + WOFF + (3 * H + U) * IN + K], v[K], go)), ...);
}

template <int WIH, int WHH, int BOFF, int IN, size_t U>
__device__ __forceinline__ void cell_unit(const float (&sm)[LDS_FLOATS], int wb,
                                          const float (&x)[IN], const float (&h)[H],
                                          float (&c)[H], float (&hn)[H]) {
    float gi = sm[wb + BOFF + 0 * H + U];
    float gf = sm[wb + BOFF + 1 * H + U];
    float gg = sm[wb + BOFF + 2 * H + U];
    float go = sm[wb + BOFF + 3 * H + U];
    dot4<WIH, IN, U>(sm, wb, x, gi, gf, gg, go, std::make_index_sequence<IN>{});
    dot4<WHH, H, U>(sm, wb, h, gi, gf, gg, go, std::make_index_sequence<H>{});
    float cn = fsigmoid(gf) * c[U] + fsigmoid(gi) * ftanh(gg);
    c[U] = cn;
    hn[U] = fsigmoid(go) * ftanh(cn);
}

template <int WIH, int WHH, int BOFF, int IN, size_t... U>
__device__ __forceinline__ void cell_impl(const float (&sm)[LDS_FLOATS], int wb,
                                          const float (&x)[IN], float (&h)[H], float (&c)[H],
                                          std::index_sequence<U...>) {
    float hn[H];
    (cell_unit<WIH, WHH, BOFF, IN, U>(sm, wb, x, h, c, hn), ...);
    ((h[U] = hn[U]), ...);
}

template <int WIH, int WHH, int BOFF, int IN>
__device__ __forceinline__ void cell(const float (&sm)[LDS_FLOATS], int wb,
                                     const float (&x)[IN], float (&h)[H], float (&c)[H]) {
    cell_impl<WIH, WHH, BOFF, IN>(sm, wb, x, h, c, std::make_index_sequence<H>{});
}

template <int WOFF, size_t J, int LD, int NV, size_t... K>
__device__ __forceinline__ float mlp_dot(const float (&sm)[LDS_FLOATS], int wb, const float (&v)[NV],
                                         float a, std::index_sequence<K...>) {
    ((a = fmaf(sm[wb + WOFF + J * LD + K], v[K], a)), ...);
    return a;
}

template <size_t... J>
__device__ __forceinline__ void mlp_l1(const float (&sm)[LDS_FLOATS], int wb,
                                       const float (&h)[H], float (&z)[10], std::index_sequence<J...>) {
    ((z[J] = fmaxf(mlp_dot<OFF_fW1, J, H>(sm, wb, h, sm[wb + OFF_fb1 + J],
                                          std::make_index_sequence<H>{}), 0.f)), ...);
}
template <size_t... J>
__device__ __forceinline__ void mlp_l2(const float (&sm)[LDS_FLOATS], int wb,
                                       const float (&z1)[10], float (&z2)[10], std::index_sequence<J...>) {
    ((z2[J] = fmaxf(mlp_dot<OFF_fW2, J, 10>(sm, wb, z1, sm[wb + OFF_fb2 + J],
                                            std::make_index_sequence<10>{}), 0.f)), ...);
}

__global__ void __launch_bounds__(256) lstm_ar_kernel(
    const float* __restrict__ y_past, const float* __restrict__ x_past,
    const float* __restrict__ u_past, const float* __restrict__ s_past,
    const float* __restrict__ u_future,
    const float* __restrict__ Wih1_0, const float* __restrict__ Whh1_0, const float* __restrict__ b1_0,
    const float* __restrict__ Wih1_1, const float* __restrict__ Whh1_1, const float* __restrict__ b1_1,
    const float* __restrict__ Wih2_0, const float* __restrict__ Whh2_0, const float* __restrict__ b2_0,
    const float* __restrict__ Wih2_1, const float* __restrict__ Whh2_1, const float* __restrict__ b2_1,
    const float* __restrict__ fW1, const float* __restrict__ fb1,
    const float* __restrict__ fW2, const float* __restrict__ fb2,
    const float* __restrict__ fW3, const float* __restrict__ fb3,
    float* __restrict__ out, int B) {
    __shared__ __align__(16) float smem[LDS_FLOATS];
    const int tid = threadIdx.x;

    // ---- stage all weights into LDS (coalesced; 47.4 KB/block; L2-served) ----
    auto stage = [&](const float* src, int off, int n) {
        for (int i = tid; i < n; i += 256) smem[off + i] = src[i];
    };
    stage(Wih1_0, OFF_Wih1_0, 4 * H * 16);
    stage(Whh1_0, OFF_Whh1_0, 4 * H * H);
    stage(b1_0,   OFF_b1_0,   4 * H);
    stage(Wih1_1, OFF_Wih1_1, 4 * H * H);
    stage(Whh1_1, OFF_Whh1_1, 4 * H * H);
    stage(b1_1,   OFF_b1_1,   4 * H);
    stage(Wih2_0, OFF_Wih2_0, 4 * H * 4);
    stage(Whh2_0, OFF_Whh2_0, 4 * H * H);
    stage(b2_0,   OFF_b2_0,   4 * H);
    stage(Wih2_1, OFF_Wih2_1, 4 * H * H);
    stage(Whh2_1, OFF_Whh2_1, 4 * H * H);
    stage(b2_1,   OFF_b2_1,   4 * H);
    stage(fW1,    OFF_fW1,    10 * H);
    stage(fb1,    OFF_fb1,    10);
    stage(fW2,    OFF_fW2,    100);
    stage(fb2,    OFF_fb2,    10);
    stage(fW3,    OFF_fW3,    10);
    stage(fb3,    OFF_fb3,    1);
    __syncthreads();

    int b = blockIdx.x * blockDim.x + tid;
    if (b >= B) return;   // B % 256 == 0, so no thread skips the barrier above

    float h0[H], c0[H], h1[H], c1[H];
    {
        auto zero = [&](auto... u) { ((h0[u] = 0.f, c0[u] = 0.f, h1[u] = 0.f, c1[u] = 0.f), ...); };
        zero(0,1,2,3,4,5,6,7,8,9,10,11,12,13,14,15,16,17,18,19);
    }

    int wb = 0;  // laundered LDS base: re-opaqued per timestep to kill LICM hoist

    // ---- encoder over lookback T=8 (input = concat[y,x,u,s] = 16 feats) ----
#pragma clang loop unroll(disable)
    for (int t = 0; t < 8; ++t) {
        asm volatile("" : "+s"(wb));   // weights "change" each iteration
        float x[16];
        x[0] = y_past[b * 8 + t];
        {   // x_past row: 8 contiguous floats -> two float4 loads
            const float4* p = (const float4*)(x_past + (size_t)(b * 8 + t) * 8);
            float4 a0 = p[0], a1 = p[1];
            x[1] = a0.x; x[2] = a0.y; x[3] = a0.z; x[4] = a0.w;
            x[5] = a1.x; x[6] = a1.y; x[7] = a1.z; x[8] = a1.w;
        }
        {   // u_past row: 4 contiguous floats
            const float4* p = (const float4*)(u_past + (size_t)(b * 8 + t) * 4);
            float4 a0 = p[0];
            x[9] = a0.x; x[10] = a0.y; x[11] = a0.z; x[12] = a0.w;
        }
        {   // s_past row: 3 floats
            const float* p = s_past + (size_t)(b * 8 + t) * 3;
            x[13] = p[0]; x[14] = p[1]; x[15] = p[2];
        }
        cell<OFF_Wih1_0, OFF_Whh1_0, OFF_b1_0, 16>(smem, wb, x, h0, c0);
        cell<OFF_Wih1_1, OFF_Whh1_1, OFF_b1_1, H>(smem, wb, h0, h1, c1);
    }

    // ---- decoder over lookahead T=4 (input = u_future, 4 feats) + MLP head ----
#pragma clang loop unroll(disable)
    for (int t = 0; t < 4; ++t) {
        asm volatile("" : "+s"(wb));
        float x[4];
        {
            const float4* p = (const float4*)(u_future + (size_t)(b * 4 + t) * 4);
            float4 a0 = p[0];
            x[0] = a0.x; x[1] = a0.y; x[2] = a0.z; x[3] = a0.w;
        }
        cell<OFF_Wih2_0, OFF_Whh2_0, OFF_b2_0, 4>(smem, wb, x, h0, c0);
        cell<OFF_Wih2_1, OFF_Whh2_1, OFF_b2_1, H>(smem, wb, h0, h1, c1);

        // FCNN 20 -> 10 -> 10 -> 1
        float z1[10], z2[10];
        mlp_l1(smem, wb, h1, z1, std::make_index_sequence<10>{});
        mlp_l2(smem, wb, z1, z2, std::make_index_sequence<10>{});
        float o = mlp_dot<OFF_fW3, 0, 10>(smem, wb, z2, smem[wb + OFF_fb3],
                                          std::make_index_sequence<10>{});
        out[b * 4 + t] = o;
    }
}

extern "C" void kernel_launch(void* const* d_in, const int* in_sizes, int n_in,
                              void* d_out, int out_size, void* d_ws, size_t ws_size,
                              hipStream_t stream) {
    (void)n_in; (void)d_ws; (void)ws_size;
    const float* y_past   = (const float*)d_in[0];
    const float* x_past   = (const float*)d_in[1];
    const float* u_past   = (const float*)d_in[2];
    const float* s_past   = (const float*)d_in[3];
    const float* u_future = (const float*)d_in[4];
    const float* Wih1_0 = (const float*)d_in[5];
    const float* Whh1_0 = (const float*)d_in[6];
    const float* b1_0   = (const float*)d_in[7];
    const float* Wih1_1 = (const float*)d_in[8];
    const float* Whh1_1 = (const float*)d_in[9];
    const float* b1_1   = (const float*)d_in[10];
    const float* Wih2_0 = (const float*)d_in[11];
    const float* Whh2_0 = (const float*)d_in[12];
    const float* b2_0   = (const float*)d_in[13];
    const float* Wih2_1 = (const float*)d_in[14];
    const float* Whh2_1 = (const float*)d_in[15];
    const float* b2_1   = (const float*)d_in[16];
    const float* fW1 = (const float*)d_in[17];
    const float* fb1 = (const float*)d_in[18];
    const float* fW2 = (const float*)d_in[19];
    const float* fb2 = (const float*)d_in[20];
    const float* fW3 = (const float*)d_in[21];
    const float* fb3 = (const float*)d_in[22];
    float* out = (float*)d_out;

    int B = in_sizes[0] / 8;  // y_past is [B,8,1]
    (void)out_size;

    dim3 block(256);
    dim3 grid((B + 255) / 256);
    lstm_ar_kernel<<<grid, block, 0, stream>>>(
        y_past, x_past, u_past, s_past, u_future,
        Wih1_0, Whh1_0, b1_0, Wih1_1, Whh1_1, b1_1,
        Wih2_0, Whh2_0, b2_0, Wih2_1, Whh2_1, b2_1,
        fW1, fb1, fW2, fb2, fW3, fb3, out, B);
}

// Round 7
// 582.025 us; speedup vs baseline: 21.0011x; 2.2481x over previous
//
#include <hip/hip_runtime.h>
#include <utility>

#define HH 20

// Raw v_rcp_f32 (~1 ulp); threshold 1.9e-3.
__device__ __forceinline__ float fast_rcp(float x) { return __builtin_amdgcn_rcpf(x); }
__device__ __forceinline__ float fsigmoid(float x) { return fast_rcp(1.0f + __expf(-x)); }
__device__ __forceinline__ float ftanh(float x) {
    float e = __expf(2.0f * x);
    return 1.0f - 2.0f * fast_rcp(e + 1.0f);
}
// DPP quad_perm [1,0,3,2]: swap adjacent lane pairs (xor 1) on the VALU pipe.
__device__ __forceinline__ float pswap(float v) {
    return __int_as_float(__builtin_amdgcn_mov_dpp(__float_as_int(v), 0xB1, 0xF, 0xF, true));
}

// ---- LDS arena: [c-layer0 state | weights] ----------------------------------
// c0 arena first so its compile-time immediates stay small; layout
// addr = (U*2+e)*128 + local_pair  -> across a wave the 32 pairs span 32 banks
// (conflict-free); the 2 lanes of a pair broadcast the same address.
constexpr int C0SZ     = 40 * 128;                    // 20 units x 2 elems x 128 pairs
constexpr int W_Wih1_0 = C0SZ;                        // 1280
constexpr int W_Whh1_0 = W_Wih1_0 + 1280;             // 1600
constexpr int W_b1_0   = W_Whh1_0 + 1600;             // 80
constexpr int W_Wih1_1 = W_b1_0 + 80;                 // 1600
constexpr int W_Whh1_1 = W_Wih1_1 + 1600;             // 1600
constexpr int W_b1_1   = W_Whh1_1 + 1600;             // 80
constexpr int W_Wih2_0 = W_b1_1 + 80;                 // 320
constexpr int W_Whh2_0 = W_Wih2_0 + 320;              // 1600
constexpr int W_b2_0   = W_Whh2_0 + 1600;             // 80
constexpr int W_Wih2_1 = W_b2_0 + 80;                 // 1600
constexpr int W_Whh2_1 = W_Wih2_1 + 1600;             // 1600
constexpr int W_b2_1   = W_Whh2_1 + 1600;             // 80
constexpr int W_fW1    = W_b2_1 + 80;                 // 200
constexpr int W_fb1    = W_fW1 + 200;                 // 10
constexpr int W_fW2    = W_fb1 + 10;                  // 100
constexpr int W_fb2    = W_fW2 + 100;                 // 10
constexpr int W_fW3    = W_fb2 + 10;                  // 10
constexpr int W_fb3    = W_fW3 + 10;                  // 1
constexpr int LDS_TOT  = W_fb3 + 1;                   // 16971 floats = 67.9 KB

// One float4 weight chunk feeding both elements (8 FMA per ds_read_b128).
template <int IN, size_t U, size_t K>
__device__ __forceinline__ void row2_k(const float (&sm)[LDS_TOT], int rb,
                                       const float (&v0)[IN], const float (&v1)[IN],
                                       float& a0, float& a1) {
    float4 w = *(const float4*)&sm[rb + (int)(U * IN + 4 * K)];
    a0 = fmaf(w.x, v0[4 * K + 0], a0); a1 = fmaf(w.x, v1[4 * K + 0], a1);
    a0 = fmaf(w.y, v0[4 * K + 1], a0); a1 = fmaf(w.y, v1[4 * K + 1], a1);
    a0 = fmaf(w.z, v0[4 * K + 2], a0); a1 = fmaf(w.z, v1[4 * K + 2], a1);
    a0 = fmaf(w.w, v0[4 * K + 3], a0); a1 = fmaf(w.w, v1[4 * K + 3], a1);
}
template <int IN, size_t U, size_t... K>
__device__ __forceinline__ void row2(const float (&sm)[LDS_TOT], int rb,
                                     const float (&v0)[IN], const float (&v1)[IN],
                                     float& a0, float& a1, std::index_sequence<K...>) {
    (row2_k<IN, U, K>(sm, rb, v0, v1, a0, a1), ...);
}

// One LSTM unit, gate-split across a lane pair, two batch elements.
// even lane (s=0): rowA = i (rows 0+U),  rowB = f (rows 20+U), m=1 -> B=sigma
// odd  lane (s=1): rowA = o (rows 60+U), rowB = g (rows 40+U), m=2 -> B=tanh
template <int IN, bool CLDS, size_t U>
__device__ __forceinline__ void unit2(float (&sm)[LDS_TOT], int s, float m, float mm1,
                                      int wihA, int wihB, int whhA, int whhB, int bA, int bB,
                                      int cbase,
                                      const float (&x0)[IN], const float (&x1)[IN],
                                      const float (&hv0)[HH], const float (&hv1)[HH],
                                      float (&creg)[2 * HH],
                                      float (&hn0)[HH], float (&hn1)[HH]) {
    float aA0 = sm[bA + (int)U], aA1 = aA0;
    float aB0 = sm[bB + (int)U], aB1 = aB0;
    row2<IN, U>(sm, wihA, x0, x1, aA0, aA1, std::make_index_sequence<IN / 4>{});
    row2<IN, U>(sm, wihB, x0, x1, aB0, aB1, std::make_index_sequence<IN / 4>{});
    row2<HH, U>(sm, whhA, hv0, hv1, aA0, aA1, std::make_index_sequence<HH / 4>{});
    row2<HH, U>(sm, whhB, hv0, hv1, aB0, aB1, std::make_index_sequence<HH / 4>{});
    float A0 = fsigmoid(aA0), A1 = fsigmoid(aA1);
    float B0 = fmaf(m, fsigmoid(m * aB0), -mm1);   // sigma (m=1) or tanh (m=2)
    float B1 = fmaf(m, fsigmoid(m * aB1), -mm1);
    float pA0 = pswap(A0), pA1 = pswap(A1), pB0 = pswap(B0), pB1 = pswap(B1);
    // role selection: SI=sigma(i), SF=sigma(f), TG=tanh(g), SO=sigma(o)
    float SI0 = s ? pA0 : A0, SF0 = s ? pB0 : B0, TG0 = s ? B0 : pB0, SO0 = s ? A0 : pA0;
    float SI1 = s ? pA1 : A1, SF1 = s ? pB1 : B1, TG1 = s ? B1 : pB1, SO1 = s ? A1 : pA1;
    float c0old, c1old;
    if constexpr (CLDS) {
        c0old = sm[cbase + (int)(U * 2 + 0) * 128];
        c1old = sm[cbase + (int)(U * 2 + 1) * 128];
    } else {
        c0old = creg[2 * U + 0];
        c1old = creg[2 * U + 1];
    }
    float cn0 = fmaf(SF0, c0old, SI0 * TG0);
    float cn1 = fmaf(SF1, c1old, SI1 * TG1);
    if constexpr (CLDS) {
        sm[cbase + (int)(U * 2 + 0) * 128] = cn0;   // both pair-lanes write same value
        sm[cbase + (int)(U * 2 + 1) * 128] = cn1;
    } else {
        creg[2 * U + 0] = cn0;
        creg[2 * U + 1] = cn1;
    }
    hn0[U] = SO0 * ftanh(cn0);
    hn1[U] = SO1 * ftanh(cn1);
}

template <int WIH, int WHH, int BOFF, int IN, bool CLDS, size_t... U>
__device__ __forceinline__ void cell2_impl(float (&sm)[LDS_TOT], int wb, int s, float m, float mm1,
                                           int lp, const float (&x0)[IN], const float (&x1)[IN],
                                           float (&hv0)[HH], float (&hv1)[HH], float (&creg)[2 * HH],
                                           std::index_sequence<U...>) {
    int wihA = wb + WIH + (s * 60) * IN;
    int wihB = wb + WIH + (20 + s * 20) * IN;
    int whhA = wb + WHH + (s * 60) * HH;
    int whhB = wb + WHH + (20 + s * 20) * HH;
    int bA = wb + BOFF + s * 60;
    int bB = wb + BOFF + 20 + s * 20;
    float hn0[HH], hn1[HH];
    (unit2<IN, CLDS, U>(sm, s, m, mm1, wihA, wihB, whhA, whhB, bA, bB, lp,
                        x0, x1, hv0, hv1, creg, hn0, hn1), ...);
    ((hv0[U] = hn0[U]), ...);
    ((hv1[U] = hn1[U]), ...);
}

template <int WIH, int WHH, int BOFF, int IN, bool CLDS>
__device__ __forceinline__ void cell2(float (&sm)[LDS_TOT], int wb, int s, float m, float mm1,
                                      int lp, const float (&x0)[IN], const float (&x1)[IN],
                                      float (&hv0)[HH], float (&hv1)[HH], float (&creg)[2 * HH]) {
    cell2_impl<WIH, WHH, BOFF, IN, CLDS>(sm, wb, s, m, mm1, lp, x0, x1, hv0, hv1, creg,
                                         std::make_index_sequence<HH>{});
}

template <int WOFF, size_t J, int LD, int NV, size_t... K>
__device__ __forceinline__ float mlp_dot(const float (&sm)[LDS_TOT], int wb, const float (&v)[NV],
                                         float a, std::index_sequence<K...>) {
    ((a = fmaf(sm[wb + WOFF + (int)(J * LD + K)], v[K], a)), ...);
    return a;
}
template <size_t... J>
__device__ __forceinline__ void mlp_l1(const float (&sm)[LDS_TOT], int wb,
                                       const float (&h)[HH], float (&z)[10], std::index_sequence<J...>) {
    ((z[J] = fmaxf(mlp_dot<W_fW1, J, HH>(sm, wb, h, sm[wb + W_fb1 + (int)J],
                                         std::make_index_sequence<HH>{}), 0.f)), ...);
}
template <size_t... J>
__device__ __forceinline__ void mlp_l2(const float (&sm)[LDS_TOT], int wb,
                                       const float (&z1)[10], float (&z2)[10], std::index_sequence<J...>) {
    ((z2[J] = fmaxf(mlp_dot<W_fW2, J, 10>(sm, wb, z1, sm[wb + W_fb2 + (int)J],
                                          std::make_index_sequence<10>{}), 0.f)), ...);
}
template <size_t... U>
__device__ __forceinline__ void hsel(int s, const float (&h0)[HH], const float (&h1)[HH],
                                     float (&hs)[HH], std::index_sequence<U...>) {
    ((hs[U] = s ? h1[U] : h0[U]), ...);
}

// waves_per_eu(2,2): pin pressure target at 2 waves/EU (256-VGPR budget);
// grid is 2 blocks/CU anyway, so nothing is lost and the allocator has room
// for the ~220-reg live state. R5 lesson retained: wb launder per timestep.
__attribute__((amdgpu_waves_per_eu(2, 2)))
__global__ void __launch_bounds__(256) lstm_ar_kernel(
    const float* __restrict__ y_past, const float* __restrict__ x_past,
    const float* __restrict__ u_past, const float* __restrict__ s_past,
    const float* __restrict__ u_future,
    const float* __restrict__ Wih1_0, const float* __restrict__ Whh1_0, const float* __restrict__ b1_0,
    const float* __restrict__ Wih1_1, const float* __restrict__ Whh1_1, const float* __restrict__ b1_1,
    const float* __restrict__ Wih2_0, const float* __restrict__ Whh2_0, const float* __restrict__ b2_0,
    const float* __restrict__ Wih2_1, const float* __restrict__ Whh2_1, const float* __restrict__ b2_1,
    const float* __restrict__ fW1, const float* __restrict__ fb1,
    const float* __restrict__ fW2, const float* __restrict__ fb2,
    const float* __restrict__ fW3, const float* __restrict__ fb3,
    float* __restrict__ out, int B) {
    __shared__ __align__(16) float smem[LDS_TOT];
    const int tid = threadIdx.x;

    // zero layer-0 c arena, stage weights
    for (int i = tid; i < C0SZ; i += 256) smem[i] = 0.f;
    auto stage = [&](const float* src, int off, int n) {
        for (int i = tid; i < n; i += 256) smem[off + i] = src[i];
    };
    stage(Wih1_0, W_Wih1_0, 1280);
    stage(Whh1_0, W_Whh1_0, 1600);
    stage(b1_0,   W_b1_0,   80);
    stage(Wih1_1, W_Wih1_1, 1600);
    stage(Whh1_1, W_Whh1_1, 1600);
    stage(b1_1,   W_b1_1,   80);
    stage(Wih2_0, W_Wih2_0, 320);
    stage(Whh2_0, W_Whh2_0, 1600);
    stage(b2_0,   W_b2_0,   80);
    stage(Wih2_1, W_Wih2_1, 1600);
    stage(Whh2_1, W_Whh2_1, 1600);
    stage(b2_1,   W_b2_1,   80);
    stage(fW1,    W_fW1,    200);
    stage(fb1,    W_fb1,    10);
    stage(fW2,    W_fW2,    100);
    stage(fb2,    W_fb2,    10);
    stage(fW3,    W_fW3,    10);
    stage(fb3,    W_fb3,    1);
    __syncthreads();

    const int s  = tid & 1;          // gate-split half: 0 -> (i,f), 1 -> (o,g)
    const int lp = tid >> 1;         // local pair index (0..127)
    const int ebase = blockIdx.x * 256 + (tid & ~1);   // elem0 = ebase, elem1 = ebase+1
    if (ebase >= B) return;          // never taken (B % 256 == 0); after barrier, safe

    const float m   = s ? 2.0f : 1.0f;
    const float mm1 = m - 1.0f;

    float h0e0[HH], h0e1[HH], h1e0[HH], h1e1[HH], c1[2 * HH];
    {
        auto zero = [&](auto... u) {
            ((h0e0[u] = 0.f, h0e1[u] = 0.f, h1e0[u] = 0.f, h1e1[u] = 0.f,
              c1[2 * u] = 0.f, c1[2 * u + 1] = 0.f), ...);
        };
        zero(0, 1, 2, 3, 4, 5, 6, 7, 8, 9, 10, 11, 12, 13, 14, 15, 16, 17, 18, 19);
    }

    int wb = 0;  // laundered weight base: re-opaqued per timestep (kills LICM hoist)

    const int e0 = ebase, e1 = ebase + 1;

    // ---- encoder over lookback T=8 (input = concat[y,x,u,s] = 16 feats) ----
#pragma clang loop unroll(disable)
    for (int t = 0; t < 8; ++t) {
        asm volatile("" : "+s"(wb));
        float x0[16], x1[16];
        x0[0] = y_past[e0 * 8 + t];
        x1[0] = y_past[e1 * 8 + t];
        {
            const float4* p0 = (const float4*)(x_past + (size_t)(e0 * 8 + t) * 8);
            const float4* p1 = (const float4*)(x_past + (size_t)(e1 * 8 + t) * 8);
            float4 a0 = p0[0], a1 = p0[1], b0 = p1[0], b1 = p1[1];
            x0[1] = a0.x; x0[2] = a0.y; x0[3] = a0.z; x0[4] = a0.w;
            x0[5] = a1.x; x0[6] = a1.y; x0[7] = a1.z; x0[8] = a1.w;
            x1[1] = b0.x; x1[2] = b0.y; x1[3] = b0.z; x1[4] = b0.w;
            x1[5] = b1.x; x1[6] = b1.y; x1[7] = b1.z; x1[8] = b1.w;
        }
        {
            const float4* p0 = (const float4*)(u_past + (size_t)(e0 * 8 + t) * 4);
            const float4* p1 = (const float4*)(u_past + (size_t)(e1 * 8 + t) * 4);
            float4 a0 = p0[0], b0 = p1[0];
            x0[9] = a0.x; x0[10] = a0.y; x0[11] = a0.z; x0[12] = a0.w;
            x1[9] = b0.x; x1[10] = b0.y; x1[11] = b0.z; x1[12] = b0.w;
        }
        {
            const float* p0 = s_past + (size_t)(e0 * 8 + t) * 3;
            const float* p1 = s_past + (size_t)(e1 * 8 + t) * 3;
            x0[13] = p0[0]; x0[14] = p0[1]; x0[15] = p0[2];
            x1[13] = p1[0]; x1[14] = p1[1]; x1[15] = p1[2];
        }
        cell2<W_Wih1_0, W_Whh1_0, W_b1_0, 16, true>(smem, wb, s, m, mm1, lp, x0, x1, h0e0, h0e1, c1);
        cell2<W_Wih1_1, W_Whh1_1, W_b1_1, HH, false>(smem, wb, s, m, mm1, lp, h0e0, h0e1, h1e0, h1e1, c1);
    }

    // ---- decoder over lookahead T=4 (input = u_future, 4 feats) + MLP head ----
#pragma clang loop unroll(disable)
    for (int t = 0; t < 4; ++t) {
        asm volatile("" : "+s"(wb));
        float x0[4], x1[4];
        {
            const float4* p0 = (const float4*)(u_future + (size_t)(e0 * 4 + t) * 4);
            const float4* p1 = (const float4*)(u_future + (size_t)(e1 * 4 + t) * 4);
            float4 a0 = p0[0], b0 = p1[0];
            x0[0] = a0.x; x0[1] = a0.y; x0[2] = a0.z; x0[3] = a0.w;
            x1[0] = b0.x; x1[1] = b0.y; x1[2] = b0.z; x1[3] = b0.w;
        }
        cell2<W_Wih2_0, W_Whh2_0, W_b2_0, 4, true>(smem, wb, s, m, mm1, lp, x0, x1, h0e0, h0e1, c1);
        cell2<W_Wih2_1, W_Whh2_1, W_b2_1, HH, false>(smem, wb, s, m, mm1, lp, h0e0, h0e1, h1e0, h1e1, c1);

        // FCNN 20 -> 10 -> 10 -> 1 for THIS lane's own element (e = ebase + s)
        float hs[HH];
        hsel(s, h1e0, h1e1, hs, std::make_index_sequence<HH>{});
        float z1[10], z2[10];
        mlp_l1(smem, wb, hs, z1, std::make_index_sequence<10>{});
        mlp_l2(smem, wb, z1, z2, std::make_index_sequence<10>{});
        float o = mlp_dot<W_fW3, 0, 10>(smem, wb, z2, smem[wb + W_fb3],
                                        std::make_index_sequence<10>{});
        out[(ebase + s) * 4 + t] = o;
    }
}

extern "C" void kernel_launch(void* const* d_in, const int* in_sizes, int n_in,
                              void* d_out, int out_size, void* d_ws, size_t ws_size,
                              hipStream_t stream) {
    (void)n_in; (void)d_ws; (void)ws_size;
    const float* y_past   = (const float*)d_in[0];
    const float* x_past   = (const float*)d_in[1];
    const float* u_past   = (const float*)d_in[2];
    const float* s_past   = (const float*)d_in[3];
    const float* u_future = (const float*)d_in[4];
    const float* Wih1_0 = (const float*)d_in[5];
    const float* Whh1_0 = (const float*)d_in[6];
    const float* b1_0   = (const float*)d_in[7];
    const float* Wih1_1 = (const float*)d_in[8];
    const float* Whh1_1 = (const float*)d_in[9];
    const float* b1_1   = (const float*)d_in[10];
    const float* Wih2_0 = (const float*)d_in[11];
    const float* Whh2_0 = (const float*)d_in[12];
    const float* b2_0   = (const float*)d_in[13];
    const float* Wih2_1 = (const float*)d_in[14];
    const float* Whh2_1 = (const float*)d_in[15];
    const float* b2_1   = (const float*)d_in[16];
    const float* fW1 = (const float*)d_in[17];
    const float* fb1 = (const float*)d_in[18];
    const float* fW2 = (const float*)d_in[19];
    const float* fb2 = (const float*)d_in[20];
    const float* fW3 = (const float*)d_in[21];
    const float* fb3 = (const float*)d_in[22];
    float* out = (float*)d_out;

    int B = in_sizes[0] / 8;  // y_past is [B,8,1]
    (void)out_size;

    dim3 block(256);
    dim3 grid((B + 255) / 256);
    lstm_ar_kernel<<<grid, block, 0, stream>>>(
        y_past, x_past, u_past, s_past, u_future,
        Wih1_0, Whh1_0, b1_0, Wih1_1, Whh1_1, b1_1,
        Wih2_0, Whh2_0, b2_0, Wih2_1, Whh2_1, b2_1,
        fW1, fb1, fW2, fb2, fW3, fb3, out, B);
}